// Round 15
// baseline (2442.574 us; speedup 1.0000x reference)
//
#include <hip/hip_runtime.h>
#include <stdint.h>

#define B_TOT 32768
#define A_N   32
#define D_N   64
#define H_N   128
#define KD    128   // 2*D
#define BT    16
#define BT2   32
#define NT    256

// ---------------- KT: transpose + widen weights (DENSE single-k layout) -----
// W1d[a][i][h/2][p]  = W1[a][2*(h/2)+p][i]      (i<128, h<128)
// W2d[a][h][d/2][p]  = W2[a][2*(d/2)+p][h]      (h<128, d<64)
// Wcd[i][h/2][p]     = Wr1[2*(h/2)+p][i]        (i<128)
// Wpd[d][h/2][p]     = Wr1[2*(h/2)+p][128+d]    (d<64)
__global__ __launch_bounds__(NT)
void kT(const float* __restrict__ W1, const float* __restrict__ W2,
        const float* __restrict__ Wr1,
        double* __restrict__ W1d, double* __restrict__ W2d,
        double* __restrict__ Wcd, double* __restrict__ Wpd)
{
  const int a = blockIdx.x, part = blockIdx.y, tid = threadIdx.x;
  if (part < 8) {
    for (int e = part*2048 + tid; e < (part+1)*2048; e += NT) {
      int i = e >> 7, h = e & 127;
      W1d[((size_t)a*KD + i)*H_N + (h>>1)*2 + (h&1)] =
          (double)W1[((size_t)a*H_N + h)*KD + i];
    }
  } else if (part == 8) {
    for (int e = tid; e < H_N*D_N; e += NT) {
      int h = e >> 6, d = e & 63;
      W2d[((size_t)a*H_N + h)*D_N + (d>>1)*2 + (d&1)] =
          (double)W2[((size_t)a*D_N + d)*H_N + h];
    }
  } else {
    for (int e = a*768 + tid; e < (a+1)*768; e += NT) {
      if (e < 16384) {
        int i = e >> 7, h = e & 127;
        Wcd[(size_t)i*H_N + (h>>1)*2 + (h&1)] = (double)Wr1[(size_t)h*192 + i];
      } else {
        int e2 = e - 16384; int d = e2 >> 7, h = e2 & 127;
        Wpd[(size_t)d*H_N + (h>>1)*2 + (h&1)] =
            (double)Wr1[(size_t)h*192 + 128 + d];
      }
    }
  }
}

// ---------------- K2 v15: v14 with QUAD-a phase 1 ---------------------------
// Phase 1 computes hidden for a0..a0+3 from the same ctx broadcasts (16 FMA
// per LDS read; v14 dual was 8). Per-a ctx reads 256->128. hid sets park in
// registers (~190 VGPR, fits 8 waves/CU). Each a's publish+phases sequence
// is v14-verbatim; per-output fma chains keep i/h/d-ascending order +
// pairing -> outputs bit-identical to all prior rounds.
__global__ __launch_bounds__(NT, 2)
void k2v15(const int* __restrict__ x, const float* __restrict__ cemb,
           const float* __restrict__ b1, const float* __restrict__ b2,
           const float* __restrict__ br1, const float* __restrict__ Wr2,
           const double* __restrict__ W1d, const double* __restrict__ W2d,
           const double* __restrict__ Wcd, const double* __restrict__ Wpd,
           int* __restrict__ sel)
{
  __shared__ double ctxd [BT2][KD];    // 32 KiB, persistent
  __shared__ double hidd [BT2][KD];    // 32 KiB; gr overlay in phase 3
  __shared__ double predd[BT2][D_N];   // 16 KiB; part overlay in reduce
  const int tid = threadIdx.x, b0 = blockIdx.x * BT2;

  // ---- gather ctx once (f64, exact from f32 source)
  for (int e = tid; e < BT2*KD; e += NT) {
    int r = e >> 7, i = e & 127;
    int xi = x[(b0 + r)*2 + (i >> 6)];
    ctxd[r][i] = (double)cemb[(size_t)xi*D_N + (i & 63)];
  }
  __syncthreads();

  const int lane = tid & 63;          // owns h-cols 2*lane, 2*lane+1
  const int h0   = lane * 2;
  const int rb8  = (tid >> 6) * 8;    // 8-row group (WAVE-UNIFORM)
  const int l32  = tid & 31;          // owns d-cols 2*l32, 2*l32+1 (phase 2)
  const int d0   = l32 * 2;
  const int r4   = (tid >> 5) * 4;    // 4-row group (2 addrs/wave -> free)

  // ---- hctx once per block, in REGISTERS (chain: acc=0, i asc, col pair)
  double hc[8][2];
  {
    #pragma unroll
    for (int q = 0; q < 8; ++q) { hc[q][0] = 0.0; hc[q][1] = 0.0; }
    #pragma unroll 2
    for (int i2 = 0; i2 < 64; ++i2) {
      const double2 vlo = *(const double2*)(Wcd + ((size_t)(2*i2  )*64 + lane)*2);
      const double2 vhi = *(const double2*)(Wcd + ((size_t)(2*i2+1)*64 + lane)*2);
      #pragma unroll
      for (int q = 0; q < 8; ++q) {
        const double2 c = *(const double2*)&ctxd[rb8+q][2*i2];   // uniform bcast
        hc[q][0] = fma(c.x, vlo.x, hc[q][0]); hc[q][1] = fma(c.x, vlo.y, hc[q][1]);
        hc[q][0] = fma(c.y, vhi.x, hc[q][0]); hc[q][1] = fma(c.y, vhi.y, hc[q][1]);
      }
    }
  }

  const double brx = (double)br1[h0], bry = (double)br1[h0 + 1];
  double best = 0.0; int idx = 0;     // live in threads tid<32

  // phases 2,3,reduce,argmin for one a (v14 verbatim)
  auto phases = [&](int a) {
    // ---- phase 2: preds[r,d] = hidden . W2[a,d,:] + b2  (4 rows x 2 cols)
    {
      double a2[4][2];
      const double b2x = (double)b2[a*D_N + d0];
      const double b2y = (double)b2[a*D_N + d0 + 1];
      #pragma unroll
      for (int q = 0; q < 4; ++q) { a2[q][0] = b2x; a2[q][1] = b2y; }
      const double* pw2 = W2d + (size_t)a*(H_N*D_N);
      #pragma unroll 2
      for (int h2 = 0; h2 < 64; ++h2) {
        const double2 wlo = *(const double2*)(pw2 + ((size_t)(2*h2  )*32 + l32)*2);
        const double2 whi = *(const double2*)(pw2 + ((size_t)(2*h2+1)*32 + l32)*2);
        #pragma unroll
        for (int q = 0; q < 4; ++q) {
          const double2 hv = *(const double2*)&hidd[r4+q][2*h2];  // 2-addr bcast
          a2[q][0] = fma(hv.x, wlo.x, a2[q][0]); a2[q][1] = fma(hv.x, wlo.y, a2[q][1]);
          a2[q][0] = fma(hv.y, whi.x, a2[q][0]); a2[q][1] = fma(hv.y, whi.y, a2[q][1]);
        }
      }
      #pragma unroll
      for (int q = 0; q < 4; ++q) {
        double2 o; o.x = a2[q][0]; o.y = a2[q][1];
        *(double2*)&predd[r4+q][d0] = o;          // lane-consecutive
      }
    }
    __syncthreads();

    // ---- phase 3: pp + relu + gr  (8 rows x 2 cols; hc from registers)
    {
      double pp[8][2];
      #pragma unroll
      for (int q = 0; q < 8; ++q) { pp[q][0] = 0.0; pp[q][1] = 0.0; }
      #pragma unroll 2
      for (int d2 = 0; d2 < 32; ++d2) {
        const double2 wlo = *(const double2*)(Wpd + ((size_t)(2*d2  )*64 + lane)*2);
        const double2 whi = *(const double2*)(Wpd + ((size_t)(2*d2+1)*64 + lane)*2);
        #pragma unroll
        for (int q = 0; q < 8; ++q) {
          const double2 p = *(const double2*)&predd[rb8+q][2*d2];  // uniform bcast
          pp[q][0] = fma(p.x, wlo.x, pp[q][0]); pp[q][1] = fma(p.x, wlo.y, pp[q][1]);
          pp[q][0] = fma(p.y, whi.x, pp[q][0]); pp[q][1] = fma(p.y, whi.y, pp[q][1]);
        }
      }
      double* grbuf = &hidd[0][0];     // hidd dead after phase 2 -> overlay
      #pragma unroll
      for (int q = 0; q < 8; ++q) {
        const double t0 = hc[q][0] + pp[q][0] + brx;
        const double t1 = hc[q][1] + pp[q][1] + bry;
        const double g0 = (t0 > 0.0) ? t0 : ((t0 == t0) ? 0.0 : t0);
        const double g1 = (t1 > 0.0) ? t1 : ((t1 == t1) ? 0.0 : t1);
        double2 o; o.x = g0; o.y = g1;
        *(double2*)&grbuf[(size_t)(rb8+q)*KD + h0] = o;          // lane-consec
      }
    }
    __syncthreads();

    // ---- reduce, replaying the ORIGINAL fma chain exactly (2 rows/thread)
    {
      const int r = tid >> 4, g = tid & 15;      // r = 0..15; also r+16
      const double* grbuf = &hidd[0][0];
      #pragma unroll
      for (int rr = r; rr < BT2; rr += 16) {
        double pg = 0.0;
        #pragma unroll
        for (int q = 0; q < 8; ++q) {
          const int hq = g + 16*q;
          pg = fma(grbuf[(size_t)rr*KD + hq], (double)Wr2[hq], pg);
        }
        predd[rr][g] = pg;              // part overlay (predd reads done)
      }
    }
    __syncthreads();

    // ---- np-exact argmin update (threads 0..31, one row each)
    if (tid < BT2) {
      double s2 = 0.0;
      for (int g = 0; g < 16; ++g) s2 += predd[tid][g];
      if (a == 0) { best = s2; idx = 0; }
      else if (!(best != best) && ((s2 != s2) || (s2 < best))) { best = s2; idx = a; }
    }
  };

  // publish one hid set to LDS (lane-consecutive) + barrier
  #define PUBLISH(HID) do {                                        \
    _Pragma("unroll")                                              \
    for (int q = 0; q < 8; ++q) {                                  \
      double2 o; o.x = HID[q][0]; o.y = HID[q][1];                 \
      *(double2*)&hidd[rb8+q][h0] = o;                             \
    }                                                              \
    __syncthreads();                                               \
  } while (0)

  #pragma unroll 1
  for (int a0 = 0; a0 < A_N; a0 += 4) {
    // ---- phase 1 (quad-a): hidden for a0..a0+3 from shared ctx reads
    double hidA[8][2], hidB[8][2], hidC[8][2], hidD[8][2];
    {
      #pragma unroll
      for (int q = 0; q < 8; ++q) {
        hidA[q][0] = (double)b1[(a0  )*H_N + h0]; hidA[q][1] = (double)b1[(a0  )*H_N + h0 + 1];
        hidB[q][0] = (double)b1[(a0+1)*H_N + h0]; hidB[q][1] = (double)b1[(a0+1)*H_N + h0 + 1];
        hidC[q][0] = (double)b1[(a0+2)*H_N + h0]; hidC[q][1] = (double)b1[(a0+2)*H_N + h0 + 1];
        hidD[q][0] = (double)b1[(a0+3)*H_N + h0]; hidD[q][1] = (double)b1[(a0+3)*H_N + h0 + 1];
      }
      const double* pwA = W1d + (size_t)a0*(KD*H_N);
      const double* pwB = pwA + (size_t)(KD*H_N);
      const double* pwC = pwB + (size_t)(KD*H_N);
      const double* pwD = pwC + (size_t)(KD*H_N);
      for (int i2 = 0; i2 < 64; ++i2) {
        const size_t olo = ((size_t)(2*i2  )*64 + lane)*2;
        const size_t ohi = ((size_t)(2*i2+1)*64 + lane)*2;
        const double2 wloA = *(const double2*)(pwA + olo);
        const double2 whiA = *(const double2*)(pwA + ohi);
        const double2 wloB = *(const double2*)(pwB + olo);
        const double2 whiB = *(const double2*)(pwB + ohi);
        const double2 wloC = *(const double2*)(pwC + olo);
        const double2 whiC = *(const double2*)(pwC + ohi);
        const double2 wloD = *(const double2*)(pwD + olo);
        const double2 whiD = *(const double2*)(pwD + ohi);
        #pragma unroll
        for (int q = 0; q < 8; ++q) {
          const double2 c = *(const double2*)&ctxd[rb8+q][2*i2];  // uniform bcast
          hidA[q][0] = fma(c.x, wloA.x, hidA[q][0]); hidA[q][1] = fma(c.x, wloA.y, hidA[q][1]);
          hidA[q][0] = fma(c.y, whiA.x, hidA[q][0]); hidA[q][1] = fma(c.y, whiA.y, hidA[q][1]);
          hidB[q][0] = fma(c.x, wloB.x, hidB[q][0]); hidB[q][1] = fma(c.x, wloB.y, hidB[q][1]);
          hidB[q][0] = fma(c.y, whiB.x, hidB[q][0]); hidB[q][1] = fma(c.y, whiB.y, hidB[q][1]);
          hidC[q][0] = fma(c.x, wloC.x, hidC[q][0]); hidC[q][1] = fma(c.x, wloC.y, hidC[q][1]);
          hidC[q][0] = fma(c.y, whiC.x, hidC[q][0]); hidC[q][1] = fma(c.y, whiC.y, hidC[q][1]);
          hidD[q][0] = fma(c.x, wloD.x, hidD[q][0]); hidD[q][1] = fma(c.x, wloD.y, hidD[q][1]);
          hidD[q][0] = fma(c.y, whiD.x, hidD[q][0]); hidD[q][1] = fma(c.y, whiD.y, hidD[q][1]);
        }
      }
    }
    PUBLISH(hidA); phases(a0);
    PUBLISH(hidB); phases(a0 + 1);
    PUBLISH(hidC); phases(a0 + 2);
    PUBLISH(hidD); phases(a0 + 3);
    // next iteration's hidd write is protected by the barrier after reduce
  }
  #undef PUBLISH

  if (tid < BT2) sel[b0 + tid] = idx;
}

// ---------------- K2 (round-1 proven fallback, no workspace weights) --------
__global__ __launch_bounds__(NT, 4)
void k2_fb(const int* __restrict__ x, const float* __restrict__ cemb,
           const float* __restrict__ W1, const float* __restrict__ b1,
           const float* __restrict__ W2, const float* __restrict__ b2,
           const float* __restrict__ Wr1, const float* __restrict__ br1,
           const float* __restrict__ Wr2, double* __restrict__ rew)
{
  __shared__ double ctxd [BT][KD];
  __shared__ double hidd [BT][KD];
  __shared__ double predd[BT][D_N];
  const int tid = threadIdx.x, b0 = blockIdx.x * BT, a = blockIdx.y;

  for (int e = tid; e < BT*KD; e += NT) {
    int r = e >> 7, i = e & 127;
    int xi = x[(b0 + r)*2 + (i >> 6)];
    ctxd[r][i] = (double)cemb[(size_t)xi*D_N + (i & 63)];
  }
  __syncthreads();

  const int h3 = tid & 127;
  const int rb = (tid >> 7) * 8;
  const int cg = tid & 63;
  const int r0 = (tid >> 6) * 4;

  double hid[8], hc[8];
  {
    const double b1v = (double)b1[a*H_N + h3];
    #pragma unroll
    for (int q = 0; q < 8; ++q) { hid[q] = b1v; hc[q] = 0.0; }
    const float* pw = W1 + ((size_t)a*H_N + h3)*KD;
    const float* pv = Wr1 + (size_t)h3*192;
    for (int i2 = 0; i2 < 64; ++i2) {
      const float2 wf = *(const float2*)(pw + 2*i2);
      const float2 vf = *(const float2*)(pv + 2*i2);
      const double wx = wf.x, wy = wf.y, vx = vf.x, vy = vf.y;
      #pragma unroll
      for (int q = 0; q < 8; ++q) {
        const double2 c = *(const double2*)&ctxd[rb+q][2*i2];
        hid[q] = fma(c.x, wx, hid[q]); hid[q] = fma(c.y, wy, hid[q]);
        hc[q]  = fma(c.x, vx, hc[q]);  hc[q]  = fma(c.y, vy, hc[q]);
      }
    }
  }
  __syncthreads();
  #pragma unroll
  for (int q = 0; q < 8; ++q) {
    hidd[rb+q][h3] = hid[q];
    ctxd[rb+q][h3] = hc[q];
  }
  __syncthreads();

  {
    double a2[4];
    const double b2v = (double)b2[a*D_N + cg];
    #pragma unroll
    for (int q = 0; q < 4; ++q) a2[q] = b2v;
    const float* pw = W2 + ((size_t)a*D_N + cg)*H_N;
    for (int h2 = 0; h2 < 64; ++h2) {
      const float2 wf = *(const float2*)(pw + 2*h2);
      const double wx = wf.x, wy = wf.y;
      #pragma unroll
      for (int q = 0; q < 4; ++q) {
        const double2 hv = *(const double2*)&hidd[r0+q][2*h2];
        a2[q] = fma(hv.x, wx, a2[q]); a2[q] = fma(hv.y, wy, a2[q]);
      }
    }
    #pragma unroll
    for (int q = 0; q < 4; ++q) predd[r0+q][cg] = a2[q];
  }
  __syncthreads();

  {
    double pp[8];
    #pragma unroll
    for (int q = 0; q < 8; ++q) pp[q] = 0.0;
    const float* pw = Wr1 + (size_t)h3*192 + 128;
    for (int d2 = 0; d2 < 32; ++d2) {
      const float2 wf = *(const float2*)(pw + 2*d2);
      const double wx = wf.x, wy = wf.y;
      #pragma unroll
      for (int q = 0; q < 8; ++q) {
        const double2 p = *(const double2*)&predd[rb+q][2*d2];
        pp[q] = fma(p.x, wx, pp[q]); pp[q] = fma(p.y, wy, pp[q]);
      }
    }
    const double brv = (double)br1[h3];
    double* grbuf = &hidd[0][0];
    #pragma unroll
    for (int q = 0; q < 8; ++q) {
      const double t = ctxd[rb+q][h3] + pp[q] + brv;
      const double gr = (t > 0.0) ? t : ((t == t) ? 0.0 : t);
      grbuf[(size_t)(rb+q)*KD + h3] = gr;
    }
  }
  __syncthreads();

  {
    const int r = tid >> 4, g = tid & 15;
    const double* grbuf = &hidd[0][0];
    double pg = 0.0;
    #pragma unroll
    for (int q = 0; q < 8; ++q) {
      const int hq = g + 16*q;
      pg = fma(grbuf[(size_t)r*KD + hq], (double)Wr2[hq], pg);
    }
    predd[r][g] = pg;
  }
  __syncthreads();
  if (tid < BT) {
    double s2 = 0.0;
    for (int g = 0; g < 16; ++g) s2 += predd[tid][g];
    rew[(size_t)(b0 + tid)*A_N + a] = s2;
  }
}

// ---------------- K3: sel[b] = np-exact argmin (fallback path only) ---------
__global__ __launch_bounds__(NT)
void k3_argmin(const double* __restrict__ rew, int* __restrict__ sel)
{
  int b = blockIdx.x * NT + threadIdx.x;
  if (b >= B_TOT) return;
  const double* rr = rew + (size_t)b*A_N;
  double best = rr[0]; int idx = 0;
  for (int a = 1; a < A_N; ++a) {
    double v = rr[a];
    if (!(best != best) && ((v != v) || (v < best))) { best = v; idx = a; }
  }
  sel[b] = idx;
}

// ---------------- K4: out_r[b,:] = preds[b, sel[b], :]  (f32 out) -----------
template<bool TR>
__global__ __launch_bounds__(NT)
void k4_out(const int* __restrict__ x, const float* __restrict__ cemb,
            const float* __restrict__ W1, const float* __restrict__ b1,
            const float* __restrict__ W2, const float* __restrict__ b2,
            const double* __restrict__ W1d, const double* __restrict__ W2d,
            const int* __restrict__ sel, float* __restrict__ out_r)
{
  __shared__ double ctxd[BT][KD];
  __shared__ double hidd[BT][KD];
  __shared__ int sels[BT];
  const int tid = threadIdx.x, b0 = blockIdx.x * BT;
  for (int e = tid; e < BT*KD; e += NT) {
    int r = e >> 7, i = e & 127;
    int xi = x[(b0 + r)*2 + (i >> 6)];
    ctxd[r][i] = (double)cemb[(size_t)xi*D_N + (i & 63)];
  }
  if (tid < BT) sels[tid] = sel[b0 + tid];
  __syncthreads();

  {
    const int r = tid >> 4, h0 = (tid & 15)*8, hl = h0 >> 1;
    const int a = sels[r];
    double acc[8];
    #pragma unroll
    for (int c = 0; c < 8; ++c) acc[c] = (double)b1[a*H_N + h0 + c];
    if constexpr (TR) {
      const double* pw1 = W1d + (size_t)a*(KD*H_N);
      for (int i2 = 0; i2 < 64; ++i2) {
        const double2 cv = *(const double2*)&ctxd[r][2*i2];
        #pragma unroll
        for (int j = 0; j < 4; ++j) {
          const double2 wlo = *(const double2*)(pw1 + ((size_t)(2*i2  )*64 + hl + j)*2);
          const double2 whi = *(const double2*)(pw1 + ((size_t)(2*i2+1)*64 + hl + j)*2);
          acc[2*j]   = fma(cv.x, wlo.x, acc[2*j]);
          acc[2*j+1] = fma(cv.x, wlo.y, acc[2*j+1]);
          acc[2*j]   = fma(cv.y, whi.x, acc[2*j]);
          acc[2*j+1] = fma(cv.y, whi.y, acc[2*j+1]);
        }
      }
    } else {
      for (int i = 0; i < KD; i += 4) {
        const double2 ca = *(const double2*)&ctxd[r][i];
        const double2 cb = *(const double2*)&ctxd[r][i+2];
        const double cv[4] = {ca.x, ca.y, cb.x, cb.y};
        #pragma unroll
        for (int c = 0; c < 8; ++c) {
          const float4 wf = *(const float4*)(W1 + ((size_t)a*H_N + h0 + c)*KD + i);
          acc[c] = fma(cv[0], (double)wf.x, acc[c]);
          acc[c] = fma(cv[1], (double)wf.y, acc[c]);
          acc[c] = fma(cv[2], (double)wf.z, acc[c]);
          acc[c] = fma(cv[3], (double)wf.w, acc[c]);
        }
      }
    }
    #pragma unroll
    for (int c = 0; c < 8; ++c) hidd[r][h0 + c] = acc[c];
  }
  __syncthreads();

  {
    const int dg = tid & 15, d0 = dg*4, dl = d0 >> 1, r2 = tid >> 4;
    const int a = sels[r2];
    double acc2[4];
    #pragma unroll
    for (int c = 0; c < 4; ++c) acc2[c] = (double)b2[a*D_N + d0 + c];
    if constexpr (TR) {
      const double* pw2 = W2d + (size_t)a*(H_N*D_N);
      for (int h2 = 0; h2 < 64; ++h2) {
        const double2 hv = *(const double2*)&hidd[r2][2*h2];
        #pragma unroll
        for (int j = 0; j < 2; ++j) {
          const double2 wlo = *(const double2*)(pw2 + ((size_t)(2*h2  )*32 + dl + j)*2);
          const double2 whi = *(const double2*)(pw2 + ((size_t)(2*h2+1)*32 + dl + j)*2);
          acc2[2*j]   = fma(hv.x, wlo.x, acc2[2*j]);
          acc2[2*j+1] = fma(hv.x, wlo.y, acc2[2*j+1]);
          acc2[2*j]   = fma(hv.y, whi.x, acc2[2*j]);
          acc2[2*j+1] = fma(hv.y, whi.y, acc2[2*j+1]);
        }
      }
    } else {
      for (int hh = 0; hh < H_N; hh += 4) {
        const double2 ha = *(const double2*)&hidd[r2][hh];
        const double2 hb = *(const double2*)&hidd[r2][hh+2];
        const double hv[4] = {ha.x, ha.y, hb.x, hb.y};
        #pragma unroll
        for (int c = 0; c < 4; ++c) {
          const float4 wf = *(const float4*)(W2 + ((size_t)a*D_N + d0 + c)*H_N + hh);
          acc2[c] = fma(hv[0], (double)wf.x, acc2[c]);
          acc2[c] = fma(hv[1], (double)wf.y, acc2[c]);
          acc2[c] = fma(hv[2], (double)wf.z, acc2[c]);
          acc2[c] = fma(hv[3], (double)wf.w, acc2[c]);
        }
      }
    }
    float4 o;
    o.x = (float)acc2[0]; o.y = (float)acc2[1];
    o.z = (float)acc2[2]; o.w = (float)acc2[3];
    *(float4*)(out_r + (size_t)(b0 + r2)*D_N + d0) = o;
  }
}

// ---------------- K5: wemb gather (f32 out) ---------------------------------
__global__ __launch_bounds__(NT)
void k5_wemb(const int* __restrict__ y, const float* __restrict__ wtab,
             float* __restrict__ out)
{
  int i = blockIdx.x * NT + threadIdx.x;   // over B*64
  int b = i >> 6, d = i & 63;
  out[i] = wtab[(size_t)y[b]*D_N + d];     // FLOAT32 output
}

extern "C" void kernel_launch(void* const* d_in, const int* in_sizes, int n_in,
                              void* d_out, int out_size, void* d_ws, size_t ws_size,
                              hipStream_t stream) {
  (void)in_sizes; (void)n_in; (void)out_size;
  const int*   x    = (const int*)d_in[0];
  const int*   y    = (const int*)d_in[1];
  const float* cemb = (const float*)d_in[2];
  const float* wemb = (const float*)d_in[3];
  const float* W1   = (const float*)d_in[4];
  const float* b1   = (const float*)d_in[5];
  const float* W2   = (const float*)d_in[6];
  const float* b2   = (const float*)d_in[7];
  const float* Wr1  = (const float*)d_in[8];
  const float* br1  = (const float*)d_in[9];
  const float* Wr2  = (const float*)d_in[10];
  // br2 (d_in[11]): constant shift of all rewards -> argmin-invariant; unused.

  // ws layout: rew f64[B][32] @0 (8 MiB, fallback only); sel i32[B] @8MiB;
  //            W1d f64 @9MiB (16 MiB); W2d f64 @25MiB (2 MiB);
  //            Wcd f64 @29MiB (128 KiB); Wpd @29MiB+128KiB (64 KiB)
  double* ws_rew = (double*)d_ws;
  int*    ws_sel = (int*)((char*)d_ws + (8ull<<20));
  double* W1d    = (double*)((char*)d_ws + (9ull<<20));
  double* W2d    = (double*)((char*)d_ws + (25ull<<20));
  double* Wcd    = (double*)((char*)d_ws + (29ull<<20));
  double* Wpd    = (double*)((char*)d_ws + (29ull<<20) + (128ull<<10));
  const bool tr = ws_size >= (30ull<<20);

  float* out_r    = (float*)d_out;                    // [B][64] f32
  float* out_wemb = out_r + (size_t)B_TOT * D_N;      // [B][64] f32

  if (tr) {
    kT<<<dim3(32, 10), dim3(NT), 0, stream>>>(W1, W2, Wr1, W1d, W2d, Wcd, Wpd);
    k2v15<<<dim3(B_TOT/BT2), dim3(NT), 0, stream>>>(
        x, cemb, b1, b2, br1, Wr2, W1d, W2d, Wcd, Wpd, ws_sel);
    k4_out<true><<<dim3(B_TOT/BT), dim3(NT), 0, stream>>>(
        x, cemb, W1, b1, W2, b2, W1d, W2d, ws_sel, out_r);
  } else {
    k2_fb<<<dim3(B_TOT/BT, A_N), dim3(NT), 0, stream>>>(
        x, cemb, W1, b1, W2, b2, Wr1, br1, Wr2, ws_rew);
    k3_argmin<<<dim3(B_TOT/NT), dim3(NT), 0, stream>>>(ws_rew, ws_sel);
    k4_out<false><<<dim3(B_TOT/BT), dim3(NT), 0, stream>>>(
        x, cemb, W1, b1, W2, b2, nullptr, nullptr, ws_sel, out_r);
  }
  k5_wemb<<<dim3(B_TOT*D_N/NT), dim3(NT), 0, stream>>>(y, wemb, out_wemb);
}

// Round 16
// 2190.329 us; speedup vs baseline: 1.1152x; 1.1152x over previous
//
#include <hip/hip_runtime.h>
#include <stdint.h>

#define B_TOT 32768
#define A_N   32
#define D_N   64
#define H_N   128
#define KD    128   // 2*D
#define BT    16
#define BT2   32
#define NT    256

// ---------------- KT: transpose + widen weights (DENSE single-k layout) -----
// W1d[a][i][h/2][p]  = W1[a][2*(h/2)+p][i]      (i<128, h<128)
// W2d[a][h][d/2][p]  = W2[a][2*(d/2)+p][h]      (h<128, d<64)
// Wcd[i][h/2][p]     = Wr1[2*(h/2)+p][i]        (i<128)
// Wpd[d][h/2][p]     = Wr1[2*(h/2)+p][128+d]    (d<64)
__global__ __launch_bounds__(NT)
void kT(const float* __restrict__ W1, const float* __restrict__ W2,
        const float* __restrict__ Wr1,
        double* __restrict__ W1d, double* __restrict__ W2d,
        double* __restrict__ Wcd, double* __restrict__ Wpd)
{
  const int a = blockIdx.x, part = blockIdx.y, tid = threadIdx.x;
  if (part < 8) {
    for (int e = part*2048 + tid; e < (part+1)*2048; e += NT) {
      int i = e >> 7, h = e & 127;
      W1d[((size_t)a*KD + i)*H_N + (h>>1)*2 + (h&1)] =
          (double)W1[((size_t)a*H_N + h)*KD + i];
    }
  } else if (part == 8) {
    for (int e = tid; e < H_N*D_N; e += NT) {
      int h = e >> 6, d = e & 63;
      W2d[((size_t)a*H_N + h)*D_N + (d>>1)*2 + (d&1)] =
          (double)W2[((size_t)a*D_N + d)*H_N + h];
    }
  } else {
    for (int e = a*768 + tid; e < (a+1)*768; e += NT) {
      if (e < 16384) {
        int i = e >> 7, h = e & 127;
        Wcd[(size_t)i*H_N + (h>>1)*2 + (h&1)] = (double)Wr1[(size_t)h*192 + i];
      } else {
        int e2 = e - 16384; int d = e2 >> 7, h = e2 & 127;
        Wpd[(size_t)d*H_N + (h>>1)*2 + (h&1)] =
            (double)Wr1[(size_t)h*192 + 128 + d];
      }
    }
  }
}

// ---------------- K2 v14: v11 + dual-a phase 1 (measured best) --------------
// BT2=32 rows, 8 rows x 2 cols per thread (1 B/MAC weight traffic), fused
// a-loop, register hc, in-block np-exact argmin. Phase 1 computes hidden for
// a AND a+1 from the same ctx broadcasts (8 FMA per LDS read); hidB parks in
// registers while a's phases run. Quad-a (v15) regressed via register
// spills; dual-a is the optimum of this axis. Per-output fma chains keep
// i/h/d-ascending order + pairing -> outputs bit-identical to all rounds.
__global__ __launch_bounds__(NT, 2)
void k2v14(const int* __restrict__ x, const float* __restrict__ cemb,
           const float* __restrict__ b1, const float* __restrict__ b2,
           const float* __restrict__ br1, const float* __restrict__ Wr2,
           const double* __restrict__ W1d, const double* __restrict__ W2d,
           const double* __restrict__ Wcd, const double* __restrict__ Wpd,
           int* __restrict__ sel)
{
  __shared__ double ctxd [BT2][KD];    // 32 KiB, persistent
  __shared__ double hidd [BT2][KD];    // 32 KiB; gr overlay in phase 3
  __shared__ double predd[BT2][D_N];   // 16 KiB; part overlay in reduce
  const int tid = threadIdx.x, b0 = blockIdx.x * BT2;

  // ---- gather ctx once (f64, exact from f32 source)
  for (int e = tid; e < BT2*KD; e += NT) {
    int r = e >> 7, i = e & 127;
    int xi = x[(b0 + r)*2 + (i >> 6)];
    ctxd[r][i] = (double)cemb[(size_t)xi*D_N + (i & 63)];
  }
  __syncthreads();

  const int lane = tid & 63;          // owns h-cols 2*lane, 2*lane+1
  const int h0   = lane * 2;
  const int rb8  = (tid >> 6) * 8;    // 8-row group (WAVE-UNIFORM)
  const int l32  = tid & 31;          // owns d-cols 2*l32, 2*l32+1 (phase 2)
  const int d0   = l32 * 2;
  const int r4   = (tid >> 5) * 4;    // 4-row group (2 addrs/wave -> free)

  // ---- hctx once per block, in REGISTERS (chain: acc=0, i asc, col pair)
  double hc[8][2];
  {
    #pragma unroll
    for (int q = 0; q < 8; ++q) { hc[q][0] = 0.0; hc[q][1] = 0.0; }
    #pragma unroll 2
    for (int i2 = 0; i2 < 64; ++i2) {
      const double2 vlo = *(const double2*)(Wcd + ((size_t)(2*i2  )*64 + lane)*2);
      const double2 vhi = *(const double2*)(Wcd + ((size_t)(2*i2+1)*64 + lane)*2);
      #pragma unroll
      for (int q = 0; q < 8; ++q) {
        const double2 c = *(const double2*)&ctxd[rb8+q][2*i2];   // uniform bcast
        hc[q][0] = fma(c.x, vlo.x, hc[q][0]); hc[q][1] = fma(c.x, vlo.y, hc[q][1]);
        hc[q][0] = fma(c.y, vhi.x, hc[q][0]); hc[q][1] = fma(c.y, vhi.y, hc[q][1]);
      }
    }
  }

  const double brx = (double)br1[h0], bry = (double)br1[h0 + 1];
  double best = 0.0; int idx = 0;     // live in threads tid<32

  // phases 2,3,reduce,argmin for one a
  auto phases = [&](int a) {
    // ---- phase 2: preds[r,d] = hidden . W2[a,d,:] + b2  (4 rows x 2 cols)
    {
      double a2[4][2];
      const double b2x = (double)b2[a*D_N + d0];
      const double b2y = (double)b2[a*D_N + d0 + 1];
      #pragma unroll
      for (int q = 0; q < 4; ++q) { a2[q][0] = b2x; a2[q][1] = b2y; }
      const double* pw2 = W2d + (size_t)a*(H_N*D_N);
      #pragma unroll 2
      for (int h2 = 0; h2 < 64; ++h2) {
        const double2 wlo = *(const double2*)(pw2 + ((size_t)(2*h2  )*32 + l32)*2);
        const double2 whi = *(const double2*)(pw2 + ((size_t)(2*h2+1)*32 + l32)*2);
        #pragma unroll
        for (int q = 0; q < 4; ++q) {
          const double2 hv = *(const double2*)&hidd[r4+q][2*h2];  // 2-addr bcast
          a2[q][0] = fma(hv.x, wlo.x, a2[q][0]); a2[q][1] = fma(hv.x, wlo.y, a2[q][1]);
          a2[q][0] = fma(hv.y, whi.x, a2[q][0]); a2[q][1] = fma(hv.y, whi.y, a2[q][1]);
        }
      }
      #pragma unroll
      for (int q = 0; q < 4; ++q) {
        double2 o; o.x = a2[q][0]; o.y = a2[q][1];
        *(double2*)&predd[r4+q][d0] = o;          // lane-consecutive
      }
    }
    __syncthreads();

    // ---- phase 3: pp + relu + gr  (8 rows x 2 cols; hc from registers)
    {
      double pp[8][2];
      #pragma unroll
      for (int q = 0; q < 8; ++q) { pp[q][0] = 0.0; pp[q][1] = 0.0; }
      #pragma unroll 2
      for (int d2 = 0; d2 < 32; ++d2) {
        const double2 wlo = *(const double2*)(Wpd + ((size_t)(2*d2  )*64 + lane)*2);
        const double2 whi = *(const double2*)(Wpd + ((size_t)(2*d2+1)*64 + lane)*2);
        #pragma unroll
        for (int q = 0; q < 8; ++q) {
          const double2 p = *(const double2*)&predd[rb8+q][2*d2];  // uniform bcast
          pp[q][0] = fma(p.x, wlo.x, pp[q][0]); pp[q][1] = fma(p.x, wlo.y, pp[q][1]);
          pp[q][0] = fma(p.y, whi.x, pp[q][0]); pp[q][1] = fma(p.y, whi.y, pp[q][1]);
        }
      }
      double* grbuf = &hidd[0][0];     // hidd dead after phase 2 -> overlay
      #pragma unroll
      for (int q = 0; q < 8; ++q) {
        const double t0 = hc[q][0] + pp[q][0] + brx;
        const double t1 = hc[q][1] + pp[q][1] + bry;
        const double g0 = (t0 > 0.0) ? t0 : ((t0 == t0) ? 0.0 : t0);
        const double g1 = (t1 > 0.0) ? t1 : ((t1 == t1) ? 0.0 : t1);
        double2 o; o.x = g0; o.y = g1;
        *(double2*)&grbuf[(size_t)(rb8+q)*KD + h0] = o;          // lane-consec
      }
    }
    __syncthreads();

    // ---- reduce, replaying the ORIGINAL fma chain exactly (2 rows/thread)
    {
      const int r = tid >> 4, g = tid & 15;      // r = 0..15; also r+16
      const double* grbuf = &hidd[0][0];
      #pragma unroll
      for (int rr = r; rr < BT2; rr += 16) {
        double pg = 0.0;
        #pragma unroll
        for (int q = 0; q < 8; ++q) {
          const int hq = g + 16*q;
          pg = fma(grbuf[(size_t)rr*KD + hq], (double)Wr2[hq], pg);
        }
        predd[rr][g] = pg;              // part overlay (predd reads done)
      }
    }
    __syncthreads();

    // ---- np-exact argmin update (threads 0..31, one row each)
    if (tid < BT2) {
      double s2 = 0.0;
      for (int g = 0; g < 16; ++g) s2 += predd[tid][g];
      if (a == 0) { best = s2; idx = 0; }
      else if (!(best != best) && ((s2 != s2) || (s2 < best))) { best = s2; idx = a; }
    }
  };

  #pragma unroll 1
  for (int a0 = 0; a0 < A_N; a0 += 2) {
    // ---- phase 1 (dual-a): hidden for a0 AND a0+1 from shared ctx reads
    double hidA[8][2], hidB[8][2];
    {
      const double bAx = (double)b1[a0*H_N + h0];
      const double bAy = (double)b1[a0*H_N + h0 + 1];
      const double bBx = (double)b1[(a0+1)*H_N + h0];
      const double bBy = (double)b1[(a0+1)*H_N + h0 + 1];
      #pragma unroll
      for (int q = 0; q < 8; ++q) {
        hidA[q][0] = bAx; hidA[q][1] = bAy;
        hidB[q][0] = bBx; hidB[q][1] = bBy;
      }
      const double* pwA = W1d + (size_t)a0*(KD*H_N);
      const double* pwB = pwA + (size_t)(KD*H_N);
      #pragma unroll 2
      for (int i2 = 0; i2 < 64; ++i2) {
        const double2 wloA = *(const double2*)(pwA + ((size_t)(2*i2  )*64 + lane)*2);
        const double2 whiA = *(const double2*)(pwA + ((size_t)(2*i2+1)*64 + lane)*2);
        const double2 wloB = *(const double2*)(pwB + ((size_t)(2*i2  )*64 + lane)*2);
        const double2 whiB = *(const double2*)(pwB + ((size_t)(2*i2+1)*64 + lane)*2);
        #pragma unroll
        for (int q = 0; q < 8; ++q) {
          const double2 c = *(const double2*)&ctxd[rb8+q][2*i2];  // uniform bcast
          hidA[q][0] = fma(c.x, wloA.x, hidA[q][0]); hidA[q][1] = fma(c.x, wloA.y, hidA[q][1]);
          hidA[q][0] = fma(c.y, whiA.x, hidA[q][0]); hidA[q][1] = fma(c.y, whiA.y, hidA[q][1]);
          hidB[q][0] = fma(c.x, wloB.x, hidB[q][0]); hidB[q][1] = fma(c.x, wloB.y, hidB[q][1]);
          hidB[q][0] = fma(c.y, whiB.x, hidB[q][0]); hidB[q][1] = fma(c.y, whiB.y, hidB[q][1]);
        }
      }
    }
    // a0: publish hidden, run phases
    #pragma unroll
    for (int q = 0; q < 8; ++q) {
      double2 o; o.x = hidA[q][0]; o.y = hidA[q][1];
      *(double2*)&hidd[rb8+q][h0] = o;            // lane-consecutive
    }
    __syncthreads();
    phases(a0);
    // gr reads were barrier'd inside phases; part (predd) is disjoint from hidd
    #pragma unroll
    for (int q = 0; q < 8; ++q) {
      double2 o; o.x = hidB[q][0]; o.y = hidB[q][1];
      *(double2*)&hidd[rb8+q][h0] = o;
    }
    __syncthreads();
    phases(a0 + 1);
    // next iteration's hidd write is protected by the barrier after reduce
  }

  if (tid < BT2) sel[b0 + tid] = idx;
}

// ---------------- K2 (round-1 proven fallback, no workspace weights) --------
__global__ __launch_bounds__(NT, 4)
void k2_fb(const int* __restrict__ x, const float* __restrict__ cemb,
           const float* __restrict__ W1, const float* __restrict__ b1,
           const float* __restrict__ W2, const float* __restrict__ b2,
           const float* __restrict__ Wr1, const float* __restrict__ br1,
           const float* __restrict__ Wr2, double* __restrict__ rew)
{
  __shared__ double ctxd [BT][KD];
  __shared__ double hidd [BT][KD];
  __shared__ double predd[BT][D_N];
  const int tid = threadIdx.x, b0 = blockIdx.x * BT, a = blockIdx.y;

  for (int e = tid; e < BT*KD; e += NT) {
    int r = e >> 7, i = e & 127;
    int xi = x[(b0 + r)*2 + (i >> 6)];
    ctxd[r][i] = (double)cemb[(size_t)xi*D_N + (i & 63)];
  }
  __syncthreads();

  const int h3 = tid & 127;
  const int rb = (tid >> 7) * 8;
  const int cg = tid & 63;
  const int r0 = (tid >> 6) * 4;

  double hid[8], hc[8];
  {
    const double b1v = (double)b1[a*H_N + h3];
    #pragma unroll
    for (int q = 0; q < 8; ++q) { hid[q] = b1v; hc[q] = 0.0; }
    const float* pw = W1 + ((size_t)a*H_N + h3)*KD;
    const float* pv = Wr1 + (size_t)h3*192;
    for (int i2 = 0; i2 < 64; ++i2) {
      const float2 wf = *(const float2*)(pw + 2*i2);
      const float2 vf = *(const float2*)(pv + 2*i2);
      const double wx = wf.x, wy = wf.y, vx = vf.x, vy = vf.y;
      #pragma unroll
      for (int q = 0; q < 8; ++q) {
        const double2 c = *(const double2*)&ctxd[rb+q][2*i2];
        hid[q] = fma(c.x, wx, hid[q]); hid[q] = fma(c.y, wy, hid[q]);
        hc[q]  = fma(c.x, vx, hc[q]);  hc[q]  = fma(c.y, vy, hc[q]);
      }
    }
  }
  __syncthreads();
  #pragma unroll
  for (int q = 0; q < 8; ++q) {
    hidd[rb+q][h3] = hid[q];
    ctxd[rb+q][h3] = hc[q];
  }
  __syncthreads();

  {
    double a2[4];
    const double b2v = (double)b2[a*D_N + cg];
    #pragma unroll
    for (int q = 0; q < 4; ++q) a2[q] = b2v;
    const float* pw = W2 + ((size_t)a*D_N + cg)*H_N;
    for (int h2 = 0; h2 < 64; ++h2) {
      const float2 wf = *(const float2*)(pw + 2*h2);
      const double wx = wf.x, wy = wf.y;
      #pragma unroll
      for (int q = 0; q < 4; ++q) {
        const double2 hv = *(const double2*)&hidd[r0+q][2*h2];
        a2[q] = fma(hv.x, wx, a2[q]); a2[q] = fma(hv.y, wy, a2[q]);
      }
    }
    #pragma unroll
    for (int q = 0; q < 4; ++q) predd[r0+q][cg] = a2[q];
  }
  __syncthreads();

  {
    double pp[8];
    #pragma unroll
    for (int q = 0; q < 8; ++q) pp[q] = 0.0;
    const float* pw = Wr1 + (size_t)h3*192 + 128;
    for (int d2 = 0; d2 < 32; ++d2) {
      const float2 wf = *(const float2*)(pw + 2*d2);
      const double wx = wf.x, wy = wf.y;
      #pragma unroll
      for (int q = 0; q < 8; ++q) {
        const double2 p = *(const double2*)&predd[rb+q][2*d2];
        pp[q] = fma(p.x, wx, pp[q]); pp[q] = fma(p.y, wy, pp[q]);
      }
    }
    const double brv = (double)br1[h3];
    double* grbuf = &hidd[0][0];
    #pragma unroll
    for (int q = 0; q < 8; ++q) {
      const double t = ctxd[rb+q][h3] + pp[q] + brv;
      const double gr = (t > 0.0) ? t : ((t == t) ? 0.0 : t);
      grbuf[(size_t)(rb+q)*KD + h3] = gr;
    }
  }
  __syncthreads();

  {
    const int r = tid >> 4, g = tid & 15;
    const double* grbuf = &hidd[0][0];
    double pg = 0.0;
    #pragma unroll
    for (int q = 0; q < 8; ++q) {
      const int hq = g + 16*q;
      pg = fma(grbuf[(size_t)r*KD + hq], (double)Wr2[hq], pg);
    }
    predd[r][g] = pg;
  }
  __syncthreads();
  if (tid < BT) {
    double s2 = 0.0;
    for (int g = 0; g < 16; ++g) s2 += predd[tid][g];
    rew[(size_t)(b0 + tid)*A_N + a] = s2;
  }
}

// ---------------- K3: sel[b] = np-exact argmin (fallback path only) ---------
__global__ __launch_bounds__(NT)
void k3_argmin(const double* __restrict__ rew, int* __restrict__ sel)
{
  int b = blockIdx.x * NT + threadIdx.x;
  if (b >= B_TOT) return;
  const double* rr = rew + (size_t)b*A_N;
  double best = rr[0]; int idx = 0;
  for (int a = 1; a < A_N; ++a) {
    double v = rr[a];
    if (!(best != best) && ((v != v) || (v < best))) { best = v; idx = a; }
  }
  sel[b] = idx;
}

// ---------------- K4: out_r[b,:] = preds[b, sel[b], :]  (f32 out) -----------
template<bool TR>
__global__ __launch_bounds__(NT)
void k4_out(const int* __restrict__ x, const float* __restrict__ cemb,
            const float* __restrict__ W1, const float* __restrict__ b1,
            const float* __restrict__ W2, const float* __restrict__ b2,
            const double* __restrict__ W1d, const double* __restrict__ W2d,
            const int* __restrict__ sel, float* __restrict__ out_r)
{
  __shared__ double ctxd[BT][KD];
  __shared__ double hidd[BT][KD];
  __shared__ int sels[BT];
  const int tid = threadIdx.x, b0 = blockIdx.x * BT;
  for (int e = tid; e < BT*KD; e += NT) {
    int r = e >> 7, i = e & 127;
    int xi = x[(b0 + r)*2 + (i >> 6)];
    ctxd[r][i] = (double)cemb[(size_t)xi*D_N + (i & 63)];
  }
  if (tid < BT) sels[tid] = sel[b0 + tid];
  __syncthreads();

  {
    const int r = tid >> 4, h0 = (tid & 15)*8, hl = h0 >> 1;
    const int a = sels[r];
    double acc[8];
    #pragma unroll
    for (int c = 0; c < 8; ++c) acc[c] = (double)b1[a*H_N + h0 + c];
    if constexpr (TR) {
      const double* pw1 = W1d + (size_t)a*(KD*H_N);
      for (int i2 = 0; i2 < 64; ++i2) {
        const double2 cv = *(const double2*)&ctxd[r][2*i2];
        #pragma unroll
        for (int j = 0; j < 4; ++j) {
          const double2 wlo = *(const double2*)(pw1 + ((size_t)(2*i2  )*64 + hl + j)*2);
          const double2 whi = *(const double2*)(pw1 + ((size_t)(2*i2+1)*64 + hl + j)*2);
          acc[2*j]   = fma(cv.x, wlo.x, acc[2*j]);
          acc[2*j+1] = fma(cv.x, wlo.y, acc[2*j+1]);
          acc[2*j]   = fma(cv.y, whi.x, acc[2*j]);
          acc[2*j+1] = fma(cv.y, whi.y, acc[2*j+1]);
        }
      }
    } else {
      for (int i = 0; i < KD; i += 4) {
        const double2 ca = *(const double2*)&ctxd[r][i];
        const double2 cb = *(const double2*)&ctxd[r][i+2];
        const double cv[4] = {ca.x, ca.y, cb.x, cb.y};
        #pragma unroll
        for (int c = 0; c < 8; ++c) {
          const float4 wf = *(const float4*)(W1 + ((size_t)a*H_N + h0 + c)*KD + i);
          acc[c] = fma(cv[0], (double)wf.x, acc[c]);
          acc[c] = fma(cv[1], (double)wf.y, acc[c]);
          acc[c] = fma(cv[2], (double)wf.z, acc[c]);
          acc[c] = fma(cv[3], (double)wf.w, acc[c]);
        }
      }
    }
    #pragma unroll
    for (int c = 0; c < 8; ++c) hidd[r][h0 + c] = acc[c];
  }
  __syncthreads();

  {
    const int dg = tid & 15, d0 = dg*4, dl = d0 >> 1, r2 = tid >> 4;
    const int a = sels[r2];
    double acc2[4];
    #pragma unroll
    for (int c = 0; c < 4; ++c) acc2[c] = (double)b2[a*D_N + d0 + c];
    if constexpr (TR) {
      const double* pw2 = W2d + (size_t)a*(H_N*D_N);
      for (int h2 = 0; h2 < 64; ++h2) {
        const double2 hv = *(const double2*)&hidd[r2][2*h2];
        #pragma unroll
        for (int j = 0; j < 2; ++j) {
          const double2 wlo = *(const double2*)(pw2 + ((size_t)(2*h2  )*32 + dl + j)*2);
          const double2 whi = *(const double2*)(pw2 + ((size_t)(2*h2+1)*32 + dl + j)*2);
          acc2[2*j]   = fma(hv.x, wlo.x, acc2[2*j]);
          acc2[2*j+1] = fma(hv.x, wlo.y, acc2[2*j+1]);
          acc2[2*j]   = fma(hv.y, whi.x, acc2[2*j]);
          acc2[2*j+1] = fma(hv.y, whi.y, acc2[2*j+1]);
        }
      }
    } else {
      for (int hh = 0; hh < H_N; hh += 4) {
        const double2 ha = *(const double2*)&hidd[r2][hh];
        const double2 hb = *(const double2*)&hidd[r2][hh+2];
        const double hv[4] = {ha.x, ha.y, hb.x, hb.y};
        #pragma unroll
        for (int c = 0; c < 4; ++c) {
          const float4 wf = *(const float4*)(W2 + ((size_t)a*D_N + d0 + c)*H_N + hh);
          acc2[c] = fma(hv[0], (double)wf.x, acc2[c]);
          acc2[c] = fma(hv[1], (double)wf.y, acc2[c]);
          acc2[c] = fma(hv[2], (double)wf.z, acc2[c]);
          acc2[c] = fma(hv[3], (double)wf.w, acc2[c]);
        }
      }
    }
    float4 o;
    o.x = (float)acc2[0]; o.y = (float)acc2[1];
    o.z = (float)acc2[2]; o.w = (float)acc2[3];
    *(float4*)(out_r + (size_t)(b0 + r2)*D_N + d0) = o;
  }
}

// ---------------- K5: wemb gather (f32 out) ---------------------------------
__global__ __launch_bounds__(NT)
void k5_wemb(const int* __restrict__ y, const float* __restrict__ wtab,
             float* __restrict__ out)
{
  int i = blockIdx.x * NT + threadIdx.x;   // over B*64
  int b = i >> 6, d = i & 63;
  out[i] = wtab[(size_t)y[b]*D_N + d];     // FLOAT32 output
}

extern "C" void kernel_launch(void* const* d_in, const int* in_sizes, int n_in,
                              void* d_out, int out_size, void* d_ws, size_t ws_size,
                              hipStream_t stream) {
  (void)in_sizes; (void)n_in; (void)out_size;
  const int*   x    = (const int*)d_in[0];
  const int*   y    = (const int*)d_in[1];
  const float* cemb = (const float*)d_in[2];
  const float* wemb = (const float*)d_in[3];
  const float* W1   = (const float*)d_in[4];
  const float* b1   = (const float*)d_in[5];
  const float* W2   = (const float*)d_in[6];
  const float* b2   = (const float*)d_in[7];
  const float* Wr1  = (const float*)d_in[8];
  const float* br1  = (const float*)d_in[9];
  const float* Wr2  = (const float*)d_in[10];
  // br2 (d_in[11]): constant shift of all rewards -> argmin-invariant; unused.

  // ws layout: rew f64[B][32] @0 (8 MiB, fallback only); sel i32[B] @8MiB;
  //            W1d f64 @9MiB (16 MiB); W2d f64 @25MiB (2 MiB);
  //            Wcd f64 @29MiB (128 KiB); Wpd @29MiB+128KiB (64 KiB)
  double* ws_rew = (double*)d_ws;
  int*    ws_sel = (int*)((char*)d_ws + (8ull<<20));
  double* W1d    = (double*)((char*)d_ws + (9ull<<20));
  double* W2d    = (double*)((char*)d_ws + (25ull<<20));
  double* Wcd    = (double*)((char*)d_ws + (29ull<<20));
  double* Wpd    = (double*)((char*)d_ws + (29ull<<20) + (128ull<<10));
  const bool tr = ws_size >= (30ull<<20);

  float* out_r    = (float*)d_out;                    // [B][64] f32
  float* out_wemb = out_r + (size_t)B_TOT * D_N;      // [B][64] f32

  if (tr) {
    kT<<<dim3(32, 10), dim3(NT), 0, stream>>>(W1, W2, Wr1, W1d, W2d, Wcd, Wpd);
    k2v14<<<dim3(B_TOT/BT2), dim3(NT), 0, stream>>>(
        x, cemb, b1, b2, br1, Wr2, W1d, W2d, Wcd, Wpd, ws_sel);
    k4_out<true><<<dim3(B_TOT/BT), dim3(NT), 0, stream>>>(
        x, cemb, W1, b1, W2, b2, W1d, W2d, ws_sel, out_r);
  } else {
    k2_fb<<<dim3(B_TOT/BT, A_N), dim3(NT), 0, stream>>>(
        x, cemb, W1, b1, W2, b2, Wr1, br1, Wr2, ws_rew);
    k3_argmin<<<dim3(B_TOT/NT), dim3(NT), 0, stream>>>(ws_rew, ws_sel);
    k4_out<false><<<dim3(B_TOT/BT), dim3(NT), 0, stream>>>(
        x, cemb, W1, b1, W2, b2, nullptr, nullptr, ws_sel, out_r);
  }
  k5_wemb<<<dim3(B_TOT*D_N/NT), dim3(NT), 0, stream>>>(y, wemb, out_wemb);
}